// Round 8
// baseline (549.089 us; speedup 1.0000x reference)
//
#include <hip/hip_runtime.h>

typedef unsigned short u16;
typedef unsigned int u32;
typedef __attribute__((ext_vector_type(8))) __bf16 bh8;
typedef __attribute__((ext_vector_type(4))) float fx4;

#define AS1 __attribute__((address_space(1)))
#define AS3 __attribute__((address_space(3)))

__device__ __forceinline__ void gll16(const void* g, void* l) {
  void* gg = const_cast<void*>(g);
  __builtin_amdgcn_global_load_lds((AS1 void*)gg, (AS3 void*)l, 16, 0, 0);
}

__device__ __forceinline__ u16 f2b(float f) {
  union { float f; u32 u; } v; v.f = f;
  u32 r = v.u + 0x7FFFu + ((v.u >> 16) & 1u);
  return (u16)(r >> 16);
}

__device__ __forceinline__ fx4 fzero() { fx4 z = {0.f, 0.f, 0.f, 0.f}; return z; }

#define MFMA16(a, b, c) __builtin_amdgcn_mfma_f32_16x16x32_bf16(a, b, c, 0, 0, 0)

// ---------------- cast f32 -> bf16, vectorized ----------------
__global__ void k_cast(const float* __restrict__ in, u16* __restrict__ out, int n4) {
  int i = blockIdx.x * blockDim.x + threadIdx.x;
  if (i >= n4) return;
  float4 v = reinterpret_cast<const float4*>(in)[i];
  ushort4 o;
  o.x = f2b(v.x); o.y = f2b(v.y); o.z = f2b(v.z); o.w = f2b(v.w);
  reinterpret_cast<ushort4*>(out)[i] = o;
}

// ---------------- ALL weight transposes in one launch ----------------
// Wq(2048x2048)->Wqt, Wk(2048x512)->Wkt, Wv->Wvt, Wo(2048x2048)->Wot.
__global__ void k_transpose_all(const float* __restrict__ Wq, const float* __restrict__ Wk,
                                const float* __restrict__ Wv, const float* __restrict__ Wo,
                                u16* __restrict__ Wqt, u16* __restrict__ Wkt,
                                u16* __restrict__ Wvt, u16* __restrict__ Wot) {
  __shared__ float t[32][33];
  int id = blockIdx.x;
  const float* in; u16* out; int C, bx, by;
  if (id < 4096)      { in = Wq; out = Wqt; C = 2048; bx = id & 63; by = id >> 6; }
  else if (id < 5120) { id -= 4096; in = Wk; out = Wkt; C = 512; bx = id & 15; by = id >> 4; }
  else if (id < 6144) { id -= 5120; in = Wv; out = Wvt; C = 512; bx = id & 15; by = id >> 4; }
  else                { id -= 6144; in = Wo; out = Wot; C = 2048; bx = id & 63; by = id >> 6; }
  const int R = 2048;
  int tx = threadIdx.x, ty = threadIdx.y;
  int r0 = by * 32, c0 = bx * 32;
#pragma unroll
  for (int j = 0; j < 4; j++)
    t[ty + 8 * j][tx] = in[(size_t)(r0 + ty + 8 * j) * C + c0 + tx];
  __syncthreads();
#pragma unroll
  for (int j = 0; j < 4; j++)
    out[(size_t)(c0 + ty + 8 * j) * R + r0 + tx] = f2b(t[tx][ty + 8 * j]);
}

// ---------------- transpose V (bf16): [(b*2048+s)*512 + kv*128 + d] -> [(z*128+d)*2048 + s]
__global__ void k_transpose_v(const u16* __restrict__ in, u16* __restrict__ out) {
  __shared__ u16 t[32][33];
  int tx = threadIdx.x, ty = threadIdx.y;
  int s0 = blockIdx.x * 32, d0 = blockIdx.y * 32;
  int z = blockIdx.z, b = z >> 2, kv = z & 3;
#pragma unroll
  for (int j = 0; j < 4; j++)
    t[ty + 8 * j][tx] = in[(size_t)(b * 2048 + s0 + ty + 8 * j) * 512 + kv * 128 + d0 + tx];
  __syncthreads();
#pragma unroll
  for (int j = 0; j < 4; j++)
    out[(size_t)(z * 128 + d0 + ty + 8 * j) * 2048 + s0 + tx] = t[tx][ty + 8 * j];
}

// ---------------- 256x256 GEMM core (round-6 structure: best measured) ------
__device__ __forceinline__ void gemm256(const u16* __restrict__ A, const u16* __restrict__ Bt,
                                        int bm, int bn, u16* Sm, fx4 (&acc)[8][4]) {
  u16* As = Sm;            // [2][16384]
  u16* Bs = Sm + 32768;    // [2][16384]
  const int tid = threadIdx.x;
  const int lane = tid & 63;
  const int i = lane & 15, g = lane >> 4;
  const int w = tid >> 6;
  const int wr = w >> 2, wc = w & 3;    // 2 (M) x 4 (N) waves
  const int arow0 = wr * 128 + i;
  const int brow0 = wc * 64 + i;
  const int swz = i & 7;

  auto SHALF = [&](const u16* G, int grow0, u16* Ld, int kt) {
#pragma unroll
    for (int cc = 0; cc < 2; cc++) {
      int p = tid + cc * 512;           // physical granule 0..1023 (128 rows x 8)
      int row = p >> 3;
      int lg = (p & 7) ^ (row & 7);     // logical granule for this slot
      gll16(G + (size_t)(grow0 + row) * 2048 + kt + lg * 8, Ld + p * 8);
    }
  };

  auto ITER = [&](const u16* cA, const u16* cB, u16* nA, u16* nB, int ktn, bool st) {
    bh8 bf[4][2];
#pragma unroll
    for (int nf = 0; nf < 4; nf++)
#pragma unroll
      for (int kk = 0; kk < 2; kk++)
        bf[nf][kk] = *reinterpret_cast<const bh8*>(
            cB + (brow0 + nf * 16) * 64 + (((kk * 4 + g) ^ swz) << 3));
#pragma unroll
    for (int mp = 0; mp < 4; mp++) {
      if (st && mp == 0) { SHALF(A, bm, nA, ktn); SHALF(Bt, bn, nB, ktn); }
      if (st && mp == 1) { SHALF(A, bm + 128, nA + 8192, ktn); SHALF(Bt, bn + 128, nB + 8192, ktn); }
      bh8 af[2][2];
#pragma unroll
      for (int mm = 0; mm < 2; mm++)
#pragma unroll
        for (int kk = 0; kk < 2; kk++)
          af[mm][kk] = *reinterpret_cast<const bh8*>(
              cA + (arow0 + (mp * 2 + mm) * 16) * 64 + (((kk * 4 + g) ^ swz) << 3));
      __builtin_amdgcn_s_setprio(1);
#pragma unroll
      for (int mm = 0; mm < 2; mm++)
#pragma unroll
        for (int nf = 0; nf < 4; nf++)
#pragma unroll
          for (int kk = 0; kk < 2; kk++)
            acc[mp * 2 + mm][nf] = MFMA16(af[mm][kk], bf[nf][kk], acc[mp * 2 + mm][nf]);
      __builtin_amdgcn_s_setprio(0);
    }
  };

  SHALF(A, bm, As, 0); SHALF(A, bm + 128, As + 8192, 0);
  SHALF(Bt, bn, Bs, 0); SHALF(Bt, bn + 128, Bs + 8192, 0);
  __syncthreads();
  for (int t = 0; t < 32; t += 2) {
    ITER(As, Bs, As + 16384, Bs + 16384, (t + 1) * 64, true);
    __syncthreads();
    ITER(As + 16384, Bs + 16384, As, Bs, (t + 2) * 64, t + 2 < 32);
    __syncthreads();
  }
}

// ---------------- fused QKV projection GEMM (256x256 tiles) ----------------
__global__ __launch_bounds__(512, 2) void k_proj(const u16* __restrict__ xb,
                                                 const u16* __restrict__ Wt,
                                                 u16* __restrict__ Qb, u16* __restrict__ Kb,
                                                 u16* __restrict__ Vb) {
  __shared__ __align__(16) u16 Sm[65536];
  fx4 acc[8][4];
#pragma unroll
  for (int m = 0; m < 8; m++)
#pragma unroll
    for (int n = 0; n < 4; n++) acc[m][n] = fzero();
  const int bm = blockIdx.x * 256, by = blockIdx.y, bn = by * 256;
  gemm256(xb, Wt, bm, bn, Sm, acc);

  u16* Cp; int coff, ldc; float alpha;
  if (by < 8)       { Cp = Qb; coff = by * 256;        ldc = 2048; alpha = 0.08838834764831845f; }
  else if (by < 10) { Cp = Kb; coff = (by - 8) * 256;  ldc = 512;  alpha = 1.0f; }
  else              { Cp = Vb; coff = (by - 10) * 256; ldc = 512;  alpha = 1.0f; }

  const int lane = threadIdx.x & 63, w = threadIdx.x >> 6;
  const int wr = w >> 2, wc = w & 3, i = lane & 15, g = lane >> 4;
#pragma unroll
  for (int mf = 0; mf < 8; mf++)
#pragma unroll
    for (int nf = 0; nf < 4; nf++)
#pragma unroll
      for (int r = 0; r < 4; r++) {
        int row = bm + wr * 128 + mf * 16 + 4 * g + r;
        int col = coff + wc * 64 + nf * 16 + i;
        Cp[(size_t)row * ldc + col] = f2b(acc[mf][nf][r] * alpha);
      }
}

// ---------------- output GEMM (f32 out, 256x256 tiles) ----------------
__global__ __launch_bounds__(512, 2) void k_gemm_out(const u16* __restrict__ Ob,
                                                     const u16* __restrict__ Wot,
                                                     float* __restrict__ C) {
  __shared__ __align__(16) u16 Sm[65536];
  fx4 acc[8][4];
#pragma unroll
  for (int m = 0; m < 8; m++)
#pragma unroll
    for (int n = 0; n < 4; n++) acc[m][n] = fzero();
  const int bm = blockIdx.x * 256, bn = blockIdx.y * 256;
  gemm256(Ob, Wot, bm, bn, Sm, acc);

  const int lane = threadIdx.x & 63, w = threadIdx.x >> 6;
  const int wr = w >> 2, wc = w & 3, i = lane & 15, g = lane >> 4;
#pragma unroll
  for (int mf = 0; mf < 8; mf++)
#pragma unroll
    for (int nf = 0; nf < 4; nf++)
#pragma unroll
      for (int r = 0; r < 4; r++) {
        int row = bm + wr * 128 + mf * 16 + 4 * g + r;
        int col = bn + wc * 64 + nf * 16 + i;
        C[(size_t)row * 2048 + col] = acc[mf][nf][r];
      }
}

// ---------------- flash attention v6 (causal, GQA) ----------------
// v5 structure, but V is NOT staged in LDS: PV B-fragments are read directly
// from L2-resident Vt (contiguous 16B/lane, 64B per g-quad). LDS 80->48KB ->
// 3 blocks/CU (6 waves/SIMD). __launch_bounds__(512,6) caps VGPR ~85.
__global__ __launch_bounds__(512, 6) void k_attn(const u16* __restrict__ Qb,
                                                 const u16* __restrict__ Kb,
                                                 const u16* __restrict__ Vt,
                                                 u16* __restrict__ Ob) {
  __shared__ __align__(16) u16 Ks0[64 * 128], Ks1[64 * 128];
  __shared__ __align__(16) u16 Pl[8][16 * 64];
  const int tid = threadIdx.x, lane = tid & 63, w = tid >> 6;
  const int i = lane & 15, g = lane >> 4;
  const int j = blockIdx.x;                 // 0..15
  const int head = blockIdx.y, b = blockIdx.z, kv = head >> 2;
  const bool isA = (w >= 4);                // waves 4-7: early tile j
  const int qt = isA ? j : (31 - j);
  const int qmin = qt * 64 + (w & 3) * 16;  // this wave's 16 q-rows
  const int nt = 32 - j;                    // block iteration count
  const int myNt = isA ? (j + 1) : nt;      // kv-tiles this wave consumes

  const u16* Kbb = Kb + (size_t)b * 2048 * 512 + kv * 128;
  const u16* Vbb = Vt + (size_t)(b * 4 + kv) * 128 * 2048;

  bh8 qf[4];
  {
    const u16* qp = Qb + (size_t)(b * 2048 + qmin + i) * 2048 + head * 128 + g * 8;
#pragma unroll
    for (int kb = 0; kb < 4; kb++) qf[kb] = *reinterpret_cast<const bh8*>(qp + kb * 32);
  }

  fx4 o[8];
#pragma unroll
  for (int dt = 0; dt < 8; dt++) o[dt] = fzero();
  float m[4] = {-1e30f, -1e30f, -1e30f, -1e30f};
  float lp[4] = {0.f, 0.f, 0.f, 0.f};       // per-lane PARTIAL row sums

  auto STAGE = [&](u16* Kd, int s0) {
#pragma unroll
    for (int cc = 0; cc < 2; cc++) {
      int c = tid + cc * 512;
      gll16(Kbb + (size_t)(s0 + (c >> 4)) * 512 + (((c & 15) ^ ((c >> 4) & 7)) * 8),
            Kd + c * 8);
    }
  };

  auto TILE = [&](const u16* Kbuf, int s0) {
    fx4 sc[4];
    __builtin_amdgcn_s_setprio(1);
#pragma unroll
    for (int st = 0; st < 4; st++) {
      sc[st] = fzero();
#pragma unroll
      for (int kb = 0; kb < 4; kb++) {
        bh8 kf = *reinterpret_cast<const bh8*>(Kbuf + (st * 16 + i) * 128 +
                                               (((kb * 4 + g) ^ (i & 7)) * 8));
        sc[st] = MFMA16(qf[kb], kf, sc[st]);
      }
    }
    __builtin_amdgcn_s_setprio(0);
    if (s0 + 63 > qmin) {
#pragma unroll
      for (int st = 0; st < 4; st++)
#pragma unroll
        for (int r = 0; r < 4; r++) {
          int s = s0 + st * 16 + i;
          int q = qmin + 4 * g + r;
          if (s > q) sc[st][r] = -1e30f;
        }
    }
    float pmax[4];
#pragma unroll
    for (int r = 0; r < 4; r++) {
      float v = fmaxf(fmaxf(sc[0][r], sc[1][r]), fmaxf(sc[2][r], sc[3][r]));
      v = fmaxf(v, __shfl_xor(v, 1));
      v = fmaxf(v, __shfl_xor(v, 2));
      v = fmaxf(v, __shfl_xor(v, 4));
      v = fmaxf(v, __shfl_xor(v, 8));
      pmax[r] = v;
    }
    int need = 0;
#pragma unroll
    for (int r = 0; r < 4; r++) need |= (pmax[r] > m[r] + 8.0f) ? 1 : 0;
    if (__any(need)) {
#pragma unroll
      for (int r = 0; r < 4; r++) {
        float mn = fmaxf(m[r], pmax[r]);
        float corr = __expf(m[r] - mn);
        m[r] = mn;
        lp[r] *= corr;
#pragma unroll
        for (int dt = 0; dt < 8; dt++) o[dt][r] *= corr;
      }
    }
    float p[4][4];
#pragma unroll
    for (int r = 0; r < 4; r++) {
#pragma unroll
      for (int st = 0; st < 4; st++) p[st][r] = __expf(sc[st][r] - m[r]);
      lp[r] += (p[0][r] + p[1][r]) + (p[2][r] + p[3][r]);
    }

#pragma unroll
    for (int st = 0; st < 4; st++)
#pragma unroll
      for (int r = 0; r < 4; r++) {
        int row = 4 * g + r;
        int cg = st * 2 + (i >> 3);
        Pl[w][row * 64 + ((cg ^ (row & 7)) << 3) + (i & 7)] = f2b(p[st][r]);
      }
    bh8 pf0 = *reinterpret_cast<const bh8*>(&Pl[w][i * 64 + ((g ^ (i & 7)) << 3)]);
    bh8 pf1 = *reinterpret_cast<const bh8*>(&Pl[w][i * 64 + (((4 + g) ^ (i & 7)) << 3)]);
    // PV: V B-frags direct from global (L2-resident Vt), 16B/lane contiguous
    const u16* vrow = Vbb + (size_t)i * 2048 + s0 + g * 8;
    __builtin_amdgcn_s_setprio(1);
#pragma unroll
    for (int dt = 0; dt < 8; dt++) {
      bh8 v0 = *reinterpret_cast<const bh8*>(vrow + (size_t)dt * 16 * 2048);
      bh8 v1 = *reinterpret_cast<const bh8*>(vrow + (size_t)dt * 16 * 2048 + 32);
      o[dt] = MFMA16(pf0, v0, o[dt]);
      o[dt] = MFMA16(pf1, v1, o[dt]);
    }
    __builtin_amdgcn_s_setprio(0);
  };

  STAGE(Ks0, 0);
  __syncthreads();
  for (int t = 0; t < nt; t += 2) {
    if (t + 1 < nt) STAGE(Ks1, (t + 1) * 64);
    if (t < myNt) TILE(Ks0, t * 64);
    __syncthreads();
    if (t + 1 >= nt) break;
    if (t + 2 < nt) STAGE(Ks0, (t + 2) * 64);
    if (t + 1 < myNt) TILE(Ks1, (t + 1) * 64);
    __syncthreads();
  }

#pragma unroll
  for (int r = 0; r < 4; r++) {
    float s = lp[r];
    s += __shfl_xor(s, 1);
    s += __shfl_xor(s, 2);
    s += __shfl_xor(s, 4);
    s += __shfl_xor(s, 8);
    float inv = 1.0f / s;
#pragma unroll
    for (int dt = 0; dt < 8; dt++)
      Ob[(size_t)(b * 2048 + qmin + 4 * g + r) * 2048 + head * 128 + dt * 16 + i] =
          f2b(o[dt][r] * inv);
  }
}

extern "C" void kernel_launch(void* const* d_in, const int* in_sizes, int n_in,
                              void* d_out, int out_size, void* d_ws, size_t ws_size,
                              hipStream_t stream) {
  (void)in_sizes; (void)n_in; (void)out_size; (void)ws_size;
  const float* x  = (const float*)d_in[0];
  const float* Wq = (const float*)d_in[1];
  const float* Wk = (const float*)d_in[2];
  const float* Wv = (const float*)d_in[3];
  const float* Wo = (const float*)d_in[4];

  char* ws = (char*)d_ws;
  size_t off = 0;
  auto alloc = [&](size_t bytes) {
    void* p = ws + off;
    off += (bytes + 255) & ~(size_t)255;
    return p;
  };
  u16* xb  = (u16*)alloc(8388608ull * 2);  // x bf16; reused as Ob after proj
  u16* Wqt = (u16*)alloc(4194304ull * 2);  // rows 0-2047 of concat Wt
  u16* Wkt = (u16*)alloc(1048576ull * 2);  // rows 2048-2559 (contiguous)
  u16* Wvt = (u16*)alloc(1048576ull * 2);  // rows 2560-3071 (contiguous)
  u16* Wot = (u16*)alloc(4194304ull * 2);
  u16* Qb  = (u16*)alloc(8388608ull * 2);
  u16* Kb  = (u16*)alloc(2097152ull * 2);
  u16* Vb  = (u16*)alloc(2097152ull * 2);
  u16* Vt  = (u16*)alloc(2097152ull * 2);
  u16* Ob  = xb;  // x is dead after k_proj

  k_cast<<<8192, 256, 0, stream>>>(x, xb, 2097152);
  k_transpose_all<<<10240, dim3(32, 8), 0, stream>>>(Wq, Wk, Wv, Wo, Wqt, Wkt, Wvt, Wot);
  k_proj<<<dim3(16, 12), 512, 0, stream>>>(xb, Wqt, Qb, Kb, Vb);
  k_transpose_v<<<dim3(64, 4, 8), dim3(32, 8), 0, stream>>>(Vb, Vt);
  k_attn<<<dim3(16, 16, 2), 512, 0, stream>>>(Qb, Kb, Vt, Ob);
  k_gemm_out<<<dim3(16, 8), 512, 0, stream>>>(Ob, Wot, (float*)d_out);
}

// Round 9
// 419.809 us; speedup vs baseline: 1.3079x; 1.3079x over previous
//
#include <hip/hip_runtime.h>

typedef unsigned short u16;
typedef unsigned int u32;
typedef __attribute__((ext_vector_type(8))) __bf16 bh8;
typedef __attribute__((ext_vector_type(4))) float fx4;

#define AS1 __attribute__((address_space(1)))
#define AS3 __attribute__((address_space(3)))

__device__ __forceinline__ void gll16(const void* g, void* l) {
  void* gg = const_cast<void*>(g);
  __builtin_amdgcn_global_load_lds((AS1 void*)gg, (AS3 void*)l, 16, 0, 0);
}

__device__ __forceinline__ u16 f2b(float f) {
  union { float f; u32 u; } v; v.f = f;
  u32 r = v.u + 0x7FFFu + ((v.u >> 16) & 1u);
  return (u16)(r >> 16);
}

__device__ __forceinline__ fx4 fzero() { fx4 z = {0.f, 0.f, 0.f, 0.f}; return z; }

#define MFMA16(a, b, c) __builtin_amdgcn_mfma_f32_16x16x32_bf16(a, b, c, 0, 0, 0)

// ---------------- cast f32 -> bf16, vectorized ----------------
__global__ void k_cast(const float* __restrict__ in, u16* __restrict__ out, int n4) {
  int i = blockIdx.x * blockDim.x + threadIdx.x;
  if (i >= n4) return;
  float4 v = reinterpret_cast<const float4*>(in)[i];
  ushort4 o;
  o.x = f2b(v.x); o.y = f2b(v.y); o.z = f2b(v.z); o.w = f2b(v.w);
  reinterpret_cast<ushort4*>(out)[i] = o;
}

// ---------------- ALL weight transposes in one launch ----------------
__global__ void k_transpose_all(const float* __restrict__ Wq, const float* __restrict__ Wk,
                                const float* __restrict__ Wv, const float* __restrict__ Wo,
                                u16* __restrict__ Wqt, u16* __restrict__ Wkt,
                                u16* __restrict__ Wvt, u16* __restrict__ Wot) {
  __shared__ float t[32][33];
  int id = blockIdx.x;
  const float* in; u16* out; int C, bx, by;
  if (id < 4096)      { in = Wq; out = Wqt; C = 2048; bx = id & 63; by = id >> 6; }
  else if (id < 5120) { id -= 4096; in = Wk; out = Wkt; C = 512; bx = id & 15; by = id >> 4; }
  else if (id < 6144) { id -= 5120; in = Wv; out = Wvt; C = 512; bx = id & 15; by = id >> 4; }
  else                { id -= 6144; in = Wo; out = Wot; C = 2048; bx = id & 63; by = id >> 6; }
  const int R = 2048;
  int tx = threadIdx.x, ty = threadIdx.y;
  int r0 = by * 32, c0 = bx * 32;
#pragma unroll
  for (int j = 0; j < 4; j++)
    t[ty + 8 * j][tx] = in[(size_t)(r0 + ty + 8 * j) * C + c0 + tx];
  __syncthreads();
#pragma unroll
  for (int j = 0; j < 4; j++)
    out[(size_t)(c0 + ty + 8 * j) * R + r0 + tx] = f2b(t[tx][ty + 8 * j]);
}

// ---------------- transpose V (bf16): [(b*2048+s)*512 + kv*128 + d] -> [(z*128+d)*2048 + s]
__global__ void k_transpose_v(const u16* __restrict__ in, u16* __restrict__ out) {
  __shared__ u16 t[32][33];
  int tx = threadIdx.x, ty = threadIdx.y;
  int s0 = blockIdx.x * 32, d0 = blockIdx.y * 32;
  int z = blockIdx.z, b = z >> 2, kv = z & 3;
#pragma unroll
  for (int j = 0; j < 4; j++)
    t[ty + 8 * j][tx] = in[(size_t)(b * 2048 + s0 + ty + 8 * j) * 512 + kv * 128 + d0 + tx];
  __syncthreads();
#pragma unroll
  for (int j = 0; j < 4; j++)
    out[(size_t)(z * 128 + d0 + ty + 8 * j) * 2048 + s0 + tx] = t[tx][ty + 8 * j];
}

// ---------------- 256x256 GEMM core, deep counted-vmcnt pipeline ----------
// Per K-tile: {read ALL frags (24 ds_read_b128); lgkmcnt(0)+sched_barrier+
// s_barrier (whole cur buffer dead across waves); stage tile t+2's 8 gll16
// INTO cur-parity buffer; 64 MFMA (setprio); vmcnt(8) = drain t+1's loads
// (issued one full tile ago), keep t+2's in flight; s_barrier}.
__device__ __forceinline__ void gemm256(const u16* __restrict__ A, const u16* __restrict__ Bt,
                                        int bm, int bn, u16* Sm, fx4 (&acc)[8][4]) {
  u16* As0 = Sm;          u16* As1 = Sm + 16384;
  u16* Bs0 = Sm + 32768;  u16* Bs1 = Sm + 49152;
  const int tid = threadIdx.x, lane = tid & 63;
  const int i = lane & 15, g = lane >> 4;
  const int w = tid >> 6, wr = w >> 2, wc = w & 3;
  const int arow0 = wr * 128 + i;
  const int brow0 = wc * 64 + i;
  const int swz = i & 7;
  const int srow = tid >> 3;                 // 0..63 within a 64-row chunk
  const int lg = (tid & 7) ^ (srow & 7);     // pre-swizzled source granule
  const size_t aoff = (size_t)(bm + srow) * 2048 + lg * 8;
  const size_t boff = (size_t)(bn + srow) * 2048 + lg * 8;
  const int dslot = tid * 8;

  auto STAGE = [&](int kt, u16* dA, u16* dB) {
#pragma unroll
    for (int c = 0; c < 4; c++) {
      gll16(A + aoff + (size_t)c * 64 * 2048 + kt, dA + c * 4096 + dslot);
      gll16(Bt + boff + (size_t)c * 64 * 2048 + kt, dB + c * 4096 + dslot);
    }
  };

  auto TILE = [&](u16* cA, u16* cB, int ktn, bool st, bool last) {
    bh8 bf[4][2], af[8][2];
#pragma unroll
    for (int nf = 0; nf < 4; nf++)
#pragma unroll
      for (int kk = 0; kk < 2; kk++)
        bf[nf][kk] = *reinterpret_cast<const bh8*>(
            cB + (brow0 + nf * 16) * 64 + (((kk * 4 + g) ^ swz) << 3));
#pragma unroll
    for (int mf = 0; mf < 8; mf++)
#pragma unroll
      for (int kk = 0; kk < 2; kk++)
        af[mf][kk] = *reinterpret_cast<const bh8*>(
            cA + (arow0 + mf * 16) * 64 + (((kk * 4 + g) ^ swz) << 3));
    asm volatile("s_waitcnt lgkmcnt(0)" ::: "memory");
    __builtin_amdgcn_sched_barrier(0);
    asm volatile("s_barrier" ::: "memory");     // all waves done reading cur bufs
    if (st) STAGE(ktn, cA, cB);                 // t+2 -> same-parity (now-dead) bufs
    __builtin_amdgcn_s_setprio(1);
#pragma unroll
    for (int mf = 0; mf < 8; mf++)
#pragma unroll
      for (int nf = 0; nf < 4; nf++)
#pragma unroll
        for (int kk = 0; kk < 2; kk++)
          acc[mf][nf] = MFMA16(af[mf][kk], bf[nf][kk], acc[mf][nf]);
    __builtin_amdgcn_s_setprio(0);
    if (last) asm volatile("s_waitcnt vmcnt(0)" ::: "memory");
    else      asm volatile("s_waitcnt vmcnt(8)" ::: "memory");
    asm volatile("s_barrier" ::: "memory");     // next tile's data landed
  };

  // prologue: stage tiles 0 and 1; drain tile 0's 8 (keep tile 1's in flight)
  STAGE(0, As0, Bs0);
  STAGE(64, As1, Bs1);
  asm volatile("s_waitcnt vmcnt(8)" ::: "memory");
  asm volatile("s_barrier" ::: "memory");
  for (int t = 0; t < 32; t += 2) {
    TILE(As0, Bs0, (t + 2) * 64, t + 2 < 32, t + 2 >= 32);
    TILE(As1, Bs1, (t + 3) * 64, t + 3 < 32, t + 3 >= 32);
  }
}

// ---------------- fused QKV projection GEMM (256x256 tiles) ----------------
__global__ __launch_bounds__(512, 2) void k_proj(const u16* __restrict__ xb,
                                                 const u16* __restrict__ Wt,
                                                 u16* __restrict__ Qb, u16* __restrict__ Kb,
                                                 u16* __restrict__ Vb) {
  __shared__ __align__(16) u16 Sm[65536];
  fx4 acc[8][4];
#pragma unroll
  for (int m = 0; m < 8; m++)
#pragma unroll
    for (int n = 0; n < 4; n++) acc[m][n] = fzero();
  const int bm = blockIdx.x * 256, by = blockIdx.y, bn = by * 256;
  gemm256(xb, Wt, bm, bn, Sm, acc);

  u16* Cp; int coff, ldc; float alpha;
  if (by < 8)       { Cp = Qb; coff = by * 256;        ldc = 2048; alpha = 0.08838834764831845f; }
  else if (by < 10) { Cp = Kb; coff = (by - 8) * 256;  ldc = 512;  alpha = 1.0f; }
  else              { Cp = Vb; coff = (by - 10) * 256; ldc = 512;  alpha = 1.0f; }

  const int lane = threadIdx.x & 63, w = threadIdx.x >> 6;
  const int wr = w >> 2, wc = w & 3, i = lane & 15, g = lane >> 4;
#pragma unroll
  for (int mf = 0; mf < 8; mf++)
#pragma unroll
    for (int nf = 0; nf < 4; nf++)
#pragma unroll
      for (int r = 0; r < 4; r++) {
        int row = bm + wr * 128 + mf * 16 + 4 * g + r;
        int col = coff + wc * 64 + nf * 16 + i;
        Cp[(size_t)row * ldc + col] = f2b(acc[mf][nf][r] * alpha);
      }
}

// ---------------- output GEMM (f32 out, 256x256 tiles) ----------------
__global__ __launch_bounds__(512, 2) void k_gemm_out(const u16* __restrict__ Ob,
                                                     const u16* __restrict__ Wot,
                                                     float* __restrict__ C) {
  __shared__ __align__(16) u16 Sm[65536];
  fx4 acc[8][4];
#pragma unroll
  for (int m = 0; m < 8; m++)
#pragma unroll
    for (int n = 0; n < 4; n++) acc[m][n] = fzero();
  const int bm = blockIdx.x * 256, bn = blockIdx.y * 256;
  gemm256(Ob, Wot, bm, bn, Sm, acc);

  const int lane = threadIdx.x & 63, w = threadIdx.x >> 6;
  const int wr = w >> 2, wc = w & 3, i = lane & 15, g = lane >> 4;
#pragma unroll
  for (int mf = 0; mf < 8; mf++)
#pragma unroll
    for (int nf = 0; nf < 4; nf++)
#pragma unroll
      for (int r = 0; r < 4; r++) {
        int row = bm + wr * 128 + mf * 16 + 4 * g + r;
        int col = bn + wc * 64 + nf * 16 + i;
        C[(size_t)row * 2048 + col] = acc[mf][nf][r];
      }
}

// ---------------- flash attention v5 (causal, GQA) — verified 115-120 us ----
__global__ __launch_bounds__(512, 4) void k_attn(const u16* __restrict__ Qb,
                                                 const u16* __restrict__ Kb,
                                                 const u16* __restrict__ Vt,
                                                 u16* __restrict__ Ob) {
  __shared__ __align__(16) u16 Ks0[64 * 128], Ks1[64 * 128];
  __shared__ __align__(16) u16 Vs0[128 * 64], Vs1[128 * 64];
  __shared__ __align__(16) u16 Pl[8][16 * 64];
  const int tid = threadIdx.x, lane = tid & 63, w = tid >> 6;
  const int i = lane & 15, g = lane >> 4;
  const int j = blockIdx.x;                 // 0..15
  const int head = blockIdx.y, b = blockIdx.z, kv = head >> 2;
  const bool isA = (w >= 4);                // waves 4-7: early tile j
  const int qt = isA ? j : (31 - j);
  const int qmin = qt * 64 + (w & 3) * 16;  // this wave's 16 q-rows
  const int nt = 32 - j;                    // block iteration count
  const int myNt = isA ? (j + 1) : nt;      // kv-tiles this wave consumes

  const u16* Kbb = Kb + (size_t)b * 2048 * 512 + kv * 128;
  const u16* Vbb = Vt + (size_t)(b * 4 + kv) * 128 * 2048;

  bh8 qf[4];
  {
    const u16* qp = Qb + (size_t)(b * 2048 + qmin + i) * 2048 + head * 128 + g * 8;
#pragma unroll
    for (int kb = 0; kb < 4; kb++) qf[kb] = *reinterpret_cast<const bh8*>(qp + kb * 32);
  }

  fx4 o[8];
#pragma unroll
  for (int dt = 0; dt < 8; dt++) o[dt] = fzero();
  float m[4] = {-1e30f, -1e30f, -1e30f, -1e30f};
  float lp[4] = {0.f, 0.f, 0.f, 0.f};       // per-lane PARTIAL row sums

  auto STAGE = [&](u16* Kd, u16* Vd, int s0) {
#pragma unroll
    for (int cc = 0; cc < 2; cc++) {
      int c = tid + cc * 512;
      gll16(Kbb + (size_t)(s0 + (c >> 4)) * 512 + (((c & 15) ^ ((c >> 4) & 7)) * 8),
            Kd + c * 8);
      gll16(Vbb + (size_t)(c >> 3) * 2048 + s0 + (((c & 7) ^ ((c >> 3) & 7)) * 8),
            Vd + c * 8);
    }
  };

  auto TILE = [&](const u16* Kbuf, const u16* Vbuf, int s0) {
    fx4 sc[4];
    __builtin_amdgcn_s_setprio(1);
#pragma unroll
    for (int st = 0; st < 4; st++) {
      sc[st] = fzero();
#pragma unroll
      for (int kb = 0; kb < 4; kb++) {
        bh8 kf = *reinterpret_cast<const bh8*>(Kbuf + (st * 16 + i) * 128 +
                                               (((kb * 4 + g) ^ (i & 7)) * 8));
        sc[st] = MFMA16(qf[kb], kf, sc[st]);
      }
    }
    __builtin_amdgcn_s_setprio(0);
    if (s0 + 63 > qmin) {
#pragma unroll
      for (int st = 0; st < 4; st++)
#pragma unroll
        for (int r = 0; r < 4; r++) {
          int s = s0 + st * 16 + i;
          int q = qmin + 4 * g + r;
          if (s > q) sc[st][r] = -1e30f;
        }
    }
    float pmax[4];
#pragma unroll
    for (int r = 0; r < 4; r++) {
      float v = fmaxf(fmaxf(sc[0][r], sc[1][r]), fmaxf(sc[2][r], sc[3][r]));
      v = fmaxf(v, __shfl_xor(v, 1));
      v = fmaxf(v, __shfl_xor(v, 2));
      v = fmaxf(v, __shfl_xor(v, 4));
      v = fmaxf(v, __shfl_xor(v, 8));
      pmax[r] = v;
    }
    int need = 0;
#pragma unroll
    for (int r = 0; r < 4; r++) need |= (pmax[r] > m[r] + 8.0f) ? 1 : 0;
    if (__any(need)) {
#pragma unroll
      for (int r = 0; r < 4; r++) {
        float mn = fmaxf(m[r], pmax[r]);
        float corr = __expf(m[r] - mn);
        m[r] = mn;
        lp[r] *= corr;
#pragma unroll
        for (int dt = 0; dt < 8; dt++) o[dt][r] *= corr;
      }
    }
    float p[4][4];
#pragma unroll
    for (int r = 0; r < 4; r++) {
#pragma unroll
      for (int st = 0; st < 4; st++) p[st][r] = __expf(sc[st][r] - m[r]);
      lp[r] += (p[0][r] + p[1][r]) + (p[2][r] + p[3][r]);
    }

#pragma unroll
    for (int st = 0; st < 4; st++)
#pragma unroll
      for (int r = 0; r < 4; r++) {
        int row = 4 * g + r;
        int cg = st * 2 + (i >> 3);
        Pl[w][row * 64 + ((cg ^ (row & 7)) << 3) + (i & 7)] = f2b(p[st][r]);
      }
    bh8 pf0 = *reinterpret_cast<const bh8*>(&Pl[w][i * 64 + ((g ^ (i & 7)) << 3)]);
    bh8 pf1 = *reinterpret_cast<const bh8*>(&Pl[w][i * 64 + (((4 + g) ^ (i & 7)) << 3)]);
    __builtin_amdgcn_s_setprio(1);
#pragma unroll
    for (int dt = 0; dt < 8; dt++) {
      bh8 v0 = *reinterpret_cast<const bh8*>(Vbuf + (dt * 16 + i) * 64 +
                                             ((g ^ (i & 7)) * 8));
      bh8 v1 = *reinterpret_cast<const bh8*>(Vbuf + (dt * 16 + i) * 64 +
                                             (((4 + g) ^ (i & 7)) * 8));
      o[dt] = MFMA16(pf0, v0, o[dt]);
      o[dt] = MFMA16(pf1, v1, o[dt]);
    }
    __builtin_amdgcn_s_setprio(0);
  };

  STAGE(Ks0, Vs0, 0);
  __syncthreads();
  for (int t = 0; t < nt; t += 2) {
    if (t + 1 < nt) STAGE(Ks1, Vs1, (t + 1) * 64);
    if (t < myNt) TILE(Ks0, Vs0, t * 64);
    __syncthreads();
    if (t + 1 >= nt) break;
    if (t + 2 < nt) STAGE(Ks0, Vs0, (t + 2) * 64);
    if (t + 1 < myNt) TILE(Ks1, Vs1, (t + 1) * 64);
    __syncthreads();
  }

#pragma unroll
  for (int r = 0; r < 4; r++) {
    float s = lp[r];
    s += __shfl_xor(s, 1);
    s += __shfl_xor(s, 2);
    s += __shfl_xor(s, 4);
    s += __shfl_xor(s, 8);
    float inv = 1.0f / s;
#pragma unroll
    for (int dt = 0; dt < 8; dt++)
      Ob[(size_t)(b * 2048 + qmin + 4 * g + r) * 2048 + head * 128 + dt * 16 + i] =
          f2b(o[dt][r] * inv);
  }
}

extern "C" void kernel_launch(void* const* d_in, const int* in_sizes, int n_in,
                              void* d_out, int out_size, void* d_ws, size_t ws_size,
                              hipStream_t stream) {
  (void)in_sizes; (void)n_in; (void)out_size; (void)ws_size;
  const float* x  = (const float*)d_in[0];
  const float* Wq = (const float*)d_in[1];
  const float* Wk = (const float*)d_in[2];
  const float* Wv = (const float*)d_in[3];
  const float* Wo = (const float*)d_in[4];

  char* ws = (char*)d_ws;
  size_t off = 0;
  auto alloc = [&](size_t bytes) {
    void* p = ws + off;
    off += (bytes + 255) & ~(size_t)255;
    return p;
  };
  u16* xb  = (u16*)alloc(8388608ull * 2);  // x bf16; reused as Ob after proj
  u16* Wqt = (u16*)alloc(4194304ull * 2);  // rows 0-2047 of concat Wt
  u16* Wkt = (u16*)alloc(1048576ull * 2);  // rows 2048-2559 (contiguous)
  u16* Wvt = (u16*)alloc(1048576ull * 2);  // rows 2560-3071 (contiguous)
  u16* Wot = (u16*)alloc(4194304ull * 2);
  u16* Qb  = (u16*)alloc(8388608ull * 2);
  u16* Kb  = (u16*)alloc(2097152ull * 2);
  u16* Vb  = (u16*)alloc(2097152ull * 2);
  u16* Vt  = (u16*)alloc(2097152ull * 2);
  u16* Ob  = xb;  // x is dead after k_proj

  k_cast<<<8192, 256, 0, stream>>>(x, xb, 2097152);
  k_transpose_all<<<10240, dim3(32, 8), 0, stream>>>(Wq, Wk, Wv, Wo, Wqt, Wkt, Wvt, Wot);
  k_proj<<<dim3(16, 12), 512, 0, stream>>>(xb, Wqt, Qb, Kb, Vb);
  k_transpose_v<<<dim3(64, 4, 8), dim3(32, 8), 0, stream>>>(Vb, Vt);
  k_attn<<<dim3(16, 16, 2), 512, 0, stream>>>(Qb, Kb, Vt, Ob);
  k_gemm_out<<<dim3(16, 8), 512, 0, stream>>>(Ob, Wot, (float*)d_out);
}

// Round 11
// 300.943 us; speedup vs baseline: 1.8246x; 1.3950x over previous
//
#include <hip/hip_runtime.h>

typedef unsigned short u16;
typedef unsigned int u32;
typedef __attribute__((ext_vector_type(8))) __bf16 bh8;
typedef __attribute__((ext_vector_type(4))) float fx4;

#define AS1 __attribute__((address_space(1)))
#define AS3 __attribute__((address_space(3)))

__device__ __forceinline__ void gll16(const void* g, void* l) {
  void* gg = const_cast<void*>(g);
  __builtin_amdgcn_global_load_lds((AS1 void*)gg, (AS3 void*)l, 16, 0, 0);
}

__device__ __forceinline__ u16 f2b(float f) {
  union { float f; u32 u; } v; v.f = f;
  u32 r = v.u + 0x7FFFu + ((v.u >> 16) & 1u);
  return (u16)(r >> 16);
}

__device__ __forceinline__ fx4 fzero() { fx4 z = {0.f, 0.f, 0.f, 0.f}; return z; }

#define MFMA16(a, b, c) __builtin_amdgcn_mfma_f32_16x16x32_bf16(a, b, c, 0, 0, 0)

// ---------------- prep: x cast + ALL weight transposes, one launch ----------
// blocks 0..8191: cast x (256 float4/block). blocks 8192..18431: transposes.
__global__ void k_prep(const float* __restrict__ x,
                       const float* __restrict__ Wq, const float* __restrict__ Wk,
                       const float* __restrict__ Wv, const float* __restrict__ Wo,
                       u16* __restrict__ xb,
                       u16* __restrict__ Wqt, u16* __restrict__ Wkt,
                       u16* __restrict__ Wvt, u16* __restrict__ Wot) {
  __shared__ float t[32][33];
  int id = blockIdx.x;
  if (id < 8192) {
    int i = id * 256 + threadIdx.x;
    float4 v = reinterpret_cast<const float4*>(x)[i];
    ushort4 o;
    o.x = f2b(v.x); o.y = f2b(v.y); o.z = f2b(v.z); o.w = f2b(v.w);
    reinterpret_cast<ushort4*>(xb)[i] = o;
    return;
  }
  id -= 8192;
  const float* in; u16* out; int C, bx, by;
  if (id < 4096)      { in = Wq; out = Wqt; C = 2048; bx = id & 63; by = id >> 6; }
  else if (id < 5120) { id -= 4096; in = Wk; out = Wkt; C = 512; bx = id & 15; by = id >> 4; }
  else if (id < 6144) { id -= 5120; in = Wv; out = Wvt; C = 512; bx = id & 15; by = id >> 4; }
  else                { id -= 6144; in = Wo; out = Wot; C = 2048; bx = id & 63; by = id >> 6; }
  const int R = 2048;
  int tx = threadIdx.x & 31, ty = threadIdx.x >> 5;
  int r0 = by * 32, c0 = bx * 32;
#pragma unroll
  for (int j = 0; j < 4; j++)
    t[ty + 8 * j][tx] = in[(size_t)(r0 + ty + 8 * j) * C + c0 + tx];
  __syncthreads();
#pragma unroll
  for (int j = 0; j < 4; j++)
    out[(size_t)(c0 + ty + 8 * j) * R + r0 + tx] = f2b(t[tx][ty + 8 * j]);
}

// ---------------- transpose V (bf16): [(b*2048+s)*512 + kv*128 + d] -> [(z*128+d)*2048 + s]
__global__ void k_transpose_v(const u16* __restrict__ in, u16* __restrict__ out) {
  __shared__ u16 t[32][33];
  int tx = threadIdx.x, ty = threadIdx.y;
  int s0 = blockIdx.x * 32, d0 = blockIdx.y * 32;
  int z = blockIdx.z, b = z >> 2, kv = z & 3;
#pragma unroll
  for (int j = 0; j < 4; j++)
    t[ty + 8 * j][tx] = in[(size_t)(b * 2048 + s0 + ty + 8 * j) * 512 + kv * 128 + d0 + tx];
  __syncthreads();
#pragma unroll
  for (int j = 0; j < 4; j++)
    out[(size_t)(z * 128 + d0 + ty + 8 * j) * 2048 + s0 + tx] = t[tx][ty + 8 * j];
}

// ---------------- 256xBN GEMM core (round-6 schedule, BN parameterized) -----
// 8 waves (2M x 4N), BK=64, dbuf LDS, granule-XOR swizzle via pre-swizzled
// global source. Per K-tile: 4 phases x {A-frag ds_reads + MFMA}; B-frags
// loaded once; next tile staged in phases 0-1; one __syncthreads per tile.
template <int BN>
__device__ __forceinline__ void gemm256(const u16* __restrict__ A, const u16* __restrict__ Bt,
                                        int bm, int bn, u16* Sm, fx4 (&acc)[8][BN / 64]) {
  constexpr int NF = BN / 64;          // B frags per wave (4 or 2)
  constexpr int BHALF = BN * 64;       // u16 per B buffer
  u16* As0 = Sm;          u16* As1 = Sm + 16384;
  u16* Bs0 = Sm + 32768;  u16* Bs1 = Sm + 32768 + BHALF;
  const int tid = threadIdx.x;
  const int lane = tid & 63;
  const int i = lane & 15, g = lane >> 4;
  const int w = tid >> 6;
  const int wr = w >> 2, wc = w & 3;   // 2 (M) x 4 (N) waves
  const int arow0 = wr * 128 + i;
  const int brow0 = wc * (BN / 4) + i;
  const int swz = i & 7;

  auto SHALF = [&](const u16* G, int grow0, u16* Ld, int kt) {
#pragma unroll
    for (int cc = 0; cc < 2; cc++) {
      int p = tid + cc * 512;          // physical granule 0..1023 (128 rows x 8)
      int row = p >> 3;
      int lg = (p & 7) ^ (row & 7);    // logical granule for this slot
      gll16(G + (size_t)(grow0 + row) * 2048 + kt + lg * 8, Ld + p * 8);
    }
  };

  auto ITER = [&](const u16* cA, const u16* cB, u16* nA, u16* nB, int ktn, bool st) {
    bh8 bf[NF][2];
#pragma unroll
    for (int nf = 0; nf < NF; nf++)
#pragma unroll
      for (int kk = 0; kk < 2; kk++)
        bf[nf][kk] = *reinterpret_cast<const bh8*>(
            cB + (brow0 + nf * 16) * 64 + (((kk * 4 + g) ^ swz) << 3));
#pragma unroll
    for (int mp = 0; mp < 4; mp++) {
      if (st && mp == 0) { SHALF(A, bm, nA, ktn); SHALF(Bt, bn, nB, ktn); }
      if (st && mp == 1) {
        SHALF(A, bm + 128, nA + 8192, ktn);
        if (BN == 256) SHALF(Bt, bn + 128, nB + 8192, ktn);
      }
      bh8 af[2][2];
#pragma unroll
      for (int mm = 0; mm < 2; mm++)
#pragma unroll
        for (int kk = 0; kk < 2; kk++)
          af[mm][kk] = *reinterpret_cast<const bh8*>(
              cA + (arow0 + (mp * 2 + mm) * 16) * 64 + (((kk * 4 + g) ^ swz) << 3));
      __builtin_amdgcn_s_setprio(1);
#pragma unroll
      for (int mm = 0; mm < 2; mm++)
#pragma unroll
        for (int nf = 0; nf < NF; nf++)
#pragma unroll
          for (int kk = 0; kk < 2; kk++)
            acc[mp * 2 + mm][nf] = MFMA16(af[mm][kk], bf[nf][kk], acc[mp * 2 + mm][nf]);
      __builtin_amdgcn_s_setprio(0);
    }
  };

  SHALF(A, bm, As0, 0); SHALF(A, bm + 128, As0 + 8192, 0);
  SHALF(Bt, bn, Bs0, 0);
  if (BN == 256) SHALF(Bt, bn + 128, Bs0 + 8192, 0);
  __syncthreads();
  for (int t = 0; t < 32; t += 2) {
    ITER(As0, Bs0, As1, Bs1, (t + 1) * 64, true);
    __syncthreads();
    ITER(As1, Bs1, As0, Bs0, (t + 2) * 64, t + 2 < 32);
    __syncthreads();
  }
}

// ---------------- fused QKV projection GEMM (256x256 tiles) ----------------
__global__ __launch_bounds__(512, 2) void k_proj(const u16* __restrict__ xb,
                                                 const u16* __restrict__ Wt,
                                                 u16* __restrict__ Qb, u16* __restrict__ Kb,
                                                 u16* __restrict__ Vb) {
  __shared__ __align__(16) u16 Sm[65536];
  fx4 acc[8][4];
#pragma unroll
  for (int m = 0; m < 8; m++)
#pragma unroll
    for (int n = 0; n < 4; n++) acc[m][n] = fzero();
  const int bm = blockIdx.x * 256, by = blockIdx.y, bn = by * 256;
  gemm256<256>(xb, Wt, bm, bn, Sm, acc);

  u16* Cp; int coff, ldc; float alpha;
  if (by < 8)       { Cp = Qb; coff = by * 256;        ldc = 2048; alpha = 0.08838834764831845f; }
  else if (by < 10) { Cp = Kb; coff = (by - 8) * 256;  ldc = 512;  alpha = 1.0f; }
  else              { Cp = Vb; coff = (by - 10) * 256; ldc = 512;  alpha = 1.0f; }

  const int lane = threadIdx.x & 63, w = threadIdx.x >> 6;
  const int wr = w >> 2, wc = w & 3, i = lane & 15, g = lane >> 4;
#pragma unroll
  for (int mf = 0; mf < 8; mf++)
#pragma unroll
    for (int nf = 0; nf < 4; nf++)
#pragma unroll
      for (int r = 0; r < 4; r++) {
        int row = bm + wr * 128 + mf * 16 + 4 * g + r;
        int col = coff + wc * 64 + nf * 16 + i;
        Cp[(size_t)row * ldc + col] = f2b(acc[mf][nf][r] * alpha);
      }
}

// ---------------- output GEMM (f32 out, 256x128 tiles -> 256 blocks) --------
__global__ __launch_bounds__(512, 2) void k_gemm_out(const u16* __restrict__ Ob,
                                                     const u16* __restrict__ Wot,
                                                     float* __restrict__ C) {
  __shared__ __align__(16) u16 Sm[49152];
  fx4 acc[8][2];
#pragma unroll
  for (int m = 0; m < 8; m++)
#pragma unroll
    for (int n = 0; n < 2; n++) acc[m][n] = fzero();
  const int bm = blockIdx.x * 256, bn = blockIdx.y * 128;
  gemm256<128>(Ob, Wot, bm, bn, Sm, acc);

  const int lane = threadIdx.x & 63, w = threadIdx.x >> 6;
  const int wr = w >> 2, wc = w & 3, i = lane & 15, g = lane >> 4;
#pragma unroll
  for (int mf = 0; mf < 8; mf++)
#pragma unroll
    for (int nf = 0; nf < 2; nf++)
#pragma unroll
      for (int r = 0; r < 4; r++) {
        int row = bm + wr * 128 + mf * 16 + 4 * g + r;
        int col = bn + wc * 32 + nf * 16 + i;
        C[(size_t)row * 2048 + col] = acc[mf][nf][r];
      }
}

// ---------------- flash attention v5 (causal, GQA) — verified 112-120 us ----
__global__ __launch_bounds__(512, 4) void k_attn(const u16* __restrict__ Qb,
                                                 const u16* __restrict__ Kb,
                                                 const u16* __restrict__ Vt,
                                                 u16* __restrict__ Ob) {
  __shared__ __align__(16) u16 Ks0[64 * 128], Ks1[64 * 128];
  __shared__ __align__(16) u16 Vs0[128 * 64], Vs1[128 * 64];
  __shared__ __align__(16) u16 Pl[8][16 * 64];
  const int tid = threadIdx.x, lane = tid & 63, w = tid >> 6;
  const int i = lane & 15, g = lane >> 4;
  const int j = blockIdx.x;                 // 0..15
  const int head = blockIdx.y, b = blockIdx.z, kv = head >> 2;
  const bool isA = (w >= 4);                // waves 4-7: early tile j
  const int qt = isA ? j : (31 - j);
  const int qmin = qt * 64 + (w & 3) * 16;  // this wave's 16 q-rows
  const int nt = 32 - j;                    // block iteration count
  const int myNt = isA ? (j + 1) : nt;      // kv-tiles this wave consumes

  const u16* Kbb = Kb + (size_t)b * 2048 * 512 + kv * 128;
  const u16* Vbb = Vt + (size_t)(b * 4 + kv) * 128 * 2048;

  bh8 qf[4];
  {
    const u16* qp = Qb + (size_t)(b * 2048 + qmin + i) * 2048 + head * 128 + g * 8;
#pragma unroll
    for (int kb = 0; kb < 4; kb++) qf[kb] = *reinterpret_cast<const bh8*>(qp + kb * 32);
  }

  fx4 o[8];
#pragma unroll
  for (int dt = 0; dt < 8; dt++) o[dt] = fzero();
  float m[4] = {-1e30f, -1e30f, -1e30f, -1e30f};
  float lp[4] = {0.f, 0.f, 0.f, 0.f};       // per-lane PARTIAL row sums

  auto STAGE = [&](u16* Kd, u16* Vd, int s0) {
#pragma unroll
    for (int cc = 0; cc < 2; cc++) {
      int c = tid + cc * 512;
      gll16(Kbb + (size_t)(s0 + (c >> 4)) * 512 + (((c & 15) ^ ((c >> 4) & 7)) * 8),
            Kd + c * 8);
      gll16(Vbb + (size_t)(c >> 3) * 2048 + s0 + (((c & 7) ^ ((c >> 3) & 7)) * 8),
            Vd + c * 8);
    }
  };

  auto TILE = [&](const u16* Kbuf, const u16* Vbuf, int s0) {
    fx4 sc[4];
    __builtin_amdgcn_s_setprio(1);
#pragma unroll
    for (int st = 0; st < 4; st++) {
      sc[st] = fzero();
#pragma unroll
      for (int kb = 0; kb < 4; kb++) {
        bh8 kf = *reinterpret_cast<const bh8*>(Kbuf + (st * 16 + i) * 128 +
                                               (((kb * 4 + g) ^ (i & 7)) * 8));
        sc[st] = MFMA16(qf[kb], kf, sc[st]);
      }
    }
    __builtin_amdgcn_s_setprio(0);
    if (s0 + 63 > qmin) {
#pragma unroll
      for (int st = 0; st < 4; st++)
#pragma unroll
        for (int r = 0; r < 4; r++) {
          int s = s0 + st * 16 + i;
          int q = qmin + 4 * g + r;
          if (s > q) sc[st][r] = -1e30f;
        }
    }
    float pmax[4];
#pragma unroll
    for (int r = 0; r < 4; r++) {
      float v = fmaxf(fmaxf(sc[0][r], sc[1][r]), fmaxf(sc[2][r], sc[3][r]));
      v = fmaxf(v, __shfl_xor(v, 1));
      v = fmaxf(v, __shfl_xor(v, 2));
      v = fmaxf(v, __shfl_xor(v, 4));
      v = fmaxf(v, __shfl_xor(v, 8));
      pmax[r] = v;
    }
    int need = 0;
#pragma unroll
    for (int r = 0; r < 4; r++) need |= (pmax[r] > m[r] + 8.0f) ? 1 : 0;
    if (__any(need)) {
#pragma unroll
      for (int r = 0; r < 4; r++) {
        float mn = fmaxf(m[r], pmax[r]);
        float corr = __expf(m[r] - mn);
        m[r] = mn;
        lp[r] *= corr;
#pragma unroll
        for (int dt = 0; dt < 8; dt++) o[dt][r] *= corr;
      }
    }
    float p[4][4];
#pragma unroll
    for (int r = 0; r < 4; r++) {
#pragma unroll
      for (int st = 0; st < 4; st++) p[st][r] = __expf(sc[st][r] - m[r]);
      lp[r] += (p[0][r] + p[1][r]) + (p[2][r] + p[3][r]);
    }

#pragma unroll
    for (int st = 0; st < 4; st++)
#pragma unroll
      for (int r = 0; r < 4; r++) {
        int row = 4 * g + r;
        int cg = st * 2 + (i >> 3);
        Pl[w][row * 64 + ((cg ^ (row & 7)) << 3) + (i & 7)] = f2b(p[st][r]);
      }
    bh8 pf0 = *reinterpret_cast<const bh8*>(&Pl[w][i * 64 + ((g ^ (i & 7)) << 3)]);
    bh8 pf1 = *reinterpret_cast<const bh8*>(&Pl[w][i * 64 + (((4 + g) ^ (i & 7)) << 3)]);
    __builtin_amdgcn_s_setprio(1);
#pragma unroll
    for (int dt = 0; dt < 8; dt++) {
      bh8 v0 = *reinterpret_cast<const bh8*>(Vbuf + (dt * 16 + i) * 64 +
                                             ((g ^ (i & 7)) * 8));
      bh8 v1 = *reinterpret_cast<const bh8*>(Vbuf + (dt * 16 + i) * 64 +
                                             (((4 + g) ^ (i & 7)) * 8));
      o[dt] = MFMA16(pf0, v0, o[dt]);
      o[dt] = MFMA16(pf1, v1, o[dt]);
    }
    __builtin_amdgcn_s_setprio(0);
  };

  STAGE(Ks0, Vs0, 0);
  __syncthreads();
  for (int t = 0; t < nt; t += 2) {
    if (t + 1 < nt) STAGE(Ks1, Vs1, (t + 1) * 64);
    if (t < myNt) TILE(Ks0, Vs0, t * 64);
    __syncthreads();
    if (t + 1 >= nt) break;
    if (t + 2 < nt) STAGE(Ks0, Vs0, (t + 2) * 64);
    if (t + 1 < myNt) TILE(Ks1, Vs1, (t + 1) * 64);
    __syncthreads();
  }

#pragma unroll
  for (int r = 0; r < 4; r++) {
    float s = lp[r];
    s += __shfl_xor(s, 1);
    s += __shfl_xor(s, 2);
    s += __shfl_xor(s, 4);
    s += __shfl_xor(s, 8);
    float inv = 1.0f / s;
#pragma unroll
    for (int dt = 0; dt < 8; dt++)
      Ob[(size_t)(b * 2048 + qmin + 4 * g + r) * 2048 + head * 128 + dt * 16 + i] =
          f2b(o[dt][r] * inv);
  }
}

extern "C" void kernel_launch(void* const* d_in, const int* in_sizes, int n_in,
                              void* d_out, int out_size, void* d_ws, size_t ws_size,
                              hipStream_t stream) {
  (void)in_sizes; (void)n_in; (void)out_size; (void)ws_size;
  const float* x  = (const float*)d_in[0];
  const float* Wq = (const float*)d_in[1];
  const float* Wk = (const float*)d_in[2];
  const float* Wv = (const float*)d_in[3];
  const float* Wo = (const float*)d_in[4];

  char* ws = (char*)d_ws;
  size_t off = 0;
  auto alloc = [&](size_t bytes) {
    void* p = ws + off;
    off += (bytes + 255) & ~(size_t)255;
    return p;
  };
  u16* xb  = (u16*)alloc(8388608ull * 2);  // x bf16; reused as Ob after proj
  u16* Wqt = (u16*)alloc(4194304ull * 2);  // rows 0-2047 of concat Wt
  u16* Wkt = (u16*)alloc(1048576ull * 2);  // rows 2048-2559 (contiguous)
  u16* Wvt = (u16*)alloc(1048576ull * 2);  // rows 2560-3071 (contiguous)
  u16* Wot = (u16*)alloc(4194304ull * 2);
  u16* Qb  = (u16*)alloc(8388608ull * 2);
  u16* Kb  = (u16*)alloc(2097152ull * 2);
  u16* Vb  = (u16*)alloc(2097152ull * 2);
  u16* Vt  = (u16*)alloc(2097152ull * 2);
  u16* Ob  = xb;  // x is dead after k_proj

  k_prep<<<18432, 256, 0, stream>>>(x, Wq, Wk, Wv, Wo, xb, Wqt, Wkt, Wvt, Wot);
  k_proj<<<dim3(16, 12), 512, 0, stream>>>(xb, Wqt, Qb, Kb, Vb);
  k_transpose_v<<<dim3(64, 4, 8), dim3(32, 8), 0, stream>>>(Vb, Vt);
  k_attn<<<dim3(16, 16, 2), 512, 0, stream>>>(Qb, Kb, Vt, Ob);
  k_gemm_out<<<dim3(16, 16), 512, 0, stream>>>(Ob, Wot, (float*)d_out);
}